// Round 1
// baseline (2497.484 us; speedup 1.0000x reference)
//
#include <hip/hip_runtime.h>

// Problem constants (fixed instance)
#define TDIM 4096
#define BDIM 256
#define ADIM 26
#define SDIM 4

// ws layout: le [T][B][S] floats at offset 0 (16 MB), alpha [T][B][S] at +16MB.

__device__ __forceinline__ float lse2f(float a, float b) {
    float m = fmaxf(a, b);
    return m + __logf(__expf(a - m) + __expf(b - m));
}
__device__ __forceinline__ float lse3f(float a, float b, float c) {
    float m = fmaxf(fmaxf(a, b), c);
    return m + __logf(__expf(a - m) + __expf(b - m) + __expf(c - m));
}

// ---------------- Kernel A: log_emit ----------------
// One thread per (b,t). idx = b*T + t (t fastest -> contiguous-ish x reads).
// Writes le[t][b][s] (scattered float4, small array).
__global__ void le_kernel(const float* __restrict__ x,
                          const float* __restrict__ emit,
                          float* __restrict__ le) {
    __shared__ float Bmat[SDIM][ADIM];
    int tid = threadIdx.x;
    if (tid < SDIM) {
        float m = -1e30f;
        #pragma unroll
        for (int a = 0; a < ADIM; ++a) m = fmaxf(m, emit[tid * ADIM + a]);
        float tmp[ADIM];
        float z = 0.f;
        #pragma unroll
        for (int a = 0; a < ADIM; ++a) {
            float e = __expf(emit[tid * ADIM + a] - m);
            tmp[a] = e;
            z += e;
        }
        float inv = 1.f / z;
        #pragma unroll
        for (int a = 0; a < ADIM; ++a) Bmat[tid][a] = tmp[a] * inv;
    }
    __syncthreads();

    int idx = blockIdx.x * blockDim.x + tid;   // 0 .. B*T-1
    int b = idx >> 12;          // / TDIM
    int t = idx & (TDIM - 1);

    const float* xp = x + (size_t)idx * ADIM;
    float v[ADIM];
    #pragma unroll
    for (int a = 0; a < ADIM; a += 2) {
        float2 u = *reinterpret_cast<const float2*>(xp + a);
        v[a] = u.x; v[a + 1] = u.y;
    }
    float m = v[0];
    #pragma unroll
    for (int a = 1; a < ADIM; ++a) m = fmaxf(m, v[a]);
    float z = 0.f, d0 = 0.f, d1 = 0.f, d2 = 0.f, d3 = 0.f;
    #pragma unroll
    for (int a = 0; a < ADIM; ++a) {
        float e = __expf(v[a] - m);
        z += e;
        d0 = fmaf(e, Bmat[0][a], d0);
        d1 = fmaf(e, Bmat[1][a], d1);
        d2 = fmaf(e, Bmat[2][a], d2);
        d3 = fmaf(e, Bmat[3][a], d3);
    }
    float invz = 1.f / z;
    float4 r;
    r.x = __logf(fmaf(d0, invz, 1e-16f));
    r.y = __logf(fmaf(d1, invz, 1e-16f));
    r.z = __logf(fmaf(d2, invz, 1e-16f));
    r.w = __logf(fmaf(d3, invz, 1e-16f));
    *reinterpret_cast<float4*>(le + ((size_t)t * BDIM + b) * SDIM) = r;
}

// ---- shared helper: masked log-softmax of transition logits ----
struct TransA {
    float A00, A01, A02, A11, A12, A13, A22, A23, A33;
};
__device__ __forceinline__ TransA make_transA(const float* __restrict__ trans) {
    TransA A;
    {
        float l0 = trans[0], l1 = trans[1], l2 = trans[2];
        float m = fmaxf(fmaxf(l0, l1), l2);
        float lz = m + __logf(__expf(l0 - m) + __expf(l1 - m) + __expf(l2 - m));
        A.A00 = l0 - lz; A.A01 = l1 - lz; A.A02 = l2 - lz;
    }
    {
        float l1 = trans[5], l2 = trans[6], l3 = trans[7];
        float m = fmaxf(fmaxf(l1, l2), l3);
        float lz = m + __logf(__expf(l1 - m) + __expf(l2 - m) + __expf(l3 - m));
        A.A11 = l1 - lz; A.A12 = l2 - lz; A.A13 = l3 - lz;
    }
    {
        float l2 = trans[10], l3 = trans[11];
        float m = fmaxf(l2, l3);
        float lz = m + __logf(__expf(l2 - m) + __expf(l3 - m));
        A.A22 = l2 - lz; A.A23 = l3 - lz;
    }
    A.A33 = 0.f;
    return A;
}

// ---------------- Kernel B: forward recursion ----------------
// One thread per b (256 threads). alpha normalized (max-subtracted) each step.
__global__ void fwd_kernel(const float* __restrict__ le,
                           const float* __restrict__ trans,
                           const float* __restrict__ initl,
                           float* __restrict__ alpha) {
    int b = blockIdx.x * blockDim.x + threadIdx.x;
    TransA A = make_transA(trans);
    float p0, p1, p2, p3;
    {
        float i0 = initl[0], i1 = initl[1], i2 = initl[2], i3 = initl[3];
        float m = fmaxf(fmaxf(i0, i1), fmaxf(i2, i3));
        float lz = m + __logf(__expf(i0 - m) + __expf(i1 - m) + __expf(i2 - m) + __expf(i3 - m));
        p0 = i0 - lz; p1 = i1 - lz; p2 = i2 - lz; p3 = i3 - lz;
    }
    const float4* lep = reinterpret_cast<const float4*>(le) + b;   // stride BDIM per t
    float4* ap = reinterpret_cast<float4*>(alpha) + b;

    float4 e = lep[0];
    float a0 = p0 + e.x, a1 = p1 + e.y, a2 = p2 + e.z, a3 = p3 + e.w;
    float mm = fmaxf(fmaxf(a0, a1), fmaxf(a2, a3));
    a0 -= mm; a1 -= mm; a2 -= mm; a3 -= mm;
    ap[0] = make_float4(a0, a1, a2, a3);

    float4 en = lep[BDIM];   // t = 1
    for (int t = 1; t < TDIM; ++t) {
        float4 cur = en;
        if (t + 1 < TDIM) en = lep[(size_t)(t + 1) * BDIM];  // prefetch
        float n0 = a0 + A.A00;
        float n1 = lse2f(a0 + A.A01, a1 + A.A11);
        float n2 = lse3f(a0 + A.A02, a1 + A.A12, a2 + A.A22);
        float n3 = lse3f(a1 + A.A13, a2 + A.A23, a3 + A.A33);
        a0 = n0 + cur.x; a1 = n1 + cur.y; a2 = n2 + cur.z; a3 = n3 + cur.w;
        float m2 = fmaxf(fmaxf(a0, a1), fmaxf(a2, a3));
        a0 -= m2; a1 -= m2; a2 -= m2; a3 -= m2;
        ap[(size_t)t * BDIM] = make_float4(a0, a1, a2, a3);
    }
}

// ---------------- Kernel C: backward recursion + gamma + output ----------------
__global__ void bwd_kernel(const float* __restrict__ le,
                           const float* __restrict__ alpha,
                           const float* __restrict__ trans,
                           const float* __restrict__ w,   // [4][5]
                           float* __restrict__ out) {
    int b = blockIdx.x * blockDim.x + threadIdx.x;
    TransA A = make_transA(trans);
    float wv[SDIM][5];
    #pragma unroll
    for (int s = 0; s < SDIM; ++s)
        #pragma unroll
        for (int o = 0; o < 5; ++o) wv[s][o] = w[s * 5 + o];

    const float4* lep = reinterpret_cast<const float4*>(le) + b;
    const float4* ap = reinterpret_cast<const float4*>(alpha) + b;
    float* op = out + (size_t)b * TDIM * 5;

    float b0 = 0.f, b1 = 0.f, b2 = 0.f, b3 = 0.f;

    // t = T-1: beta = 0
    {
        float4 av = ap[(size_t)(TDIM - 1) * BDIM];
        float g0 = av.x, g1 = av.y, g2 = av.z, g3 = av.w;
        float m = fmaxf(fmaxf(g0, g1), fmaxf(g2, g3));
        float e0 = __expf(g0 - m), e1 = __expf(g1 - m), e2 = __expf(g2 - m), e3 = __expf(g3 - m);
        float inv = 1.f / (e0 + e1 + e2 + e3);
        e0 *= inv; e1 *= inv; e2 *= inv; e3 *= inv;
        #pragma unroll
        for (int o = 0; o < 5; ++o)
            op[(size_t)(TDIM - 1) * 5 + o] =
                fmaf(e0, wv[0][o], fmaf(e1, wv[1][o], fmaf(e2, wv[2][o], e3 * wv[3][o])));
    }

    float4 e = lep[(size_t)(TDIM - 1) * BDIM];     // le[t+1] for t = T-2
    float4 av = ap[(size_t)(TDIM - 2) * BDIM];     // alpha[t] for t = T-2
    for (int t = TDIM - 2; t >= 0; --t) {
        float4 ecur = e;
        float4 acur = av;
        if (t > 0) {                                // prefetch next iteration
            e = lep[(size_t)t * BDIM];
            av = ap[(size_t)(t - 1) * BDIM];
        }
        float f0 = ecur.x + b0, f1 = ecur.y + b1, f2 = ecur.z + b2, f3 = ecur.w + b3;
        float n0 = lse3f(A.A00 + f0, A.A01 + f1, A.A02 + f2);
        float n1 = lse3f(A.A11 + f1, A.A12 + f2, A.A13 + f3);
        float n2 = lse2f(A.A22 + f2, A.A23 + f3);
        float n3 = A.A33 + f3;
        float bm = fmaxf(fmaxf(n0, n1), fmaxf(n2, n3));
        b0 = n0 - bm; b1 = n1 - bm; b2 = n2 - bm; b3 = n3 - bm;

        float g0 = acur.x + b0, g1 = acur.y + b1, g2 = acur.z + b2, g3 = acur.w + b3;
        float m = fmaxf(fmaxf(g0, g1), fmaxf(g2, g3));
        float e0 = __expf(g0 - m), e1 = __expf(g1 - m), e2 = __expf(g2 - m), e3 = __expf(g3 - m);
        float inv = 1.f / (e0 + e1 + e2 + e3);
        e0 *= inv; e1 *= inv; e2 *= inv; e3 *= inv;
        #pragma unroll
        for (int o = 0; o < 5; ++o)
            op[(size_t)t * 5 + o] =
                fmaf(e0, wv[0][o], fmaf(e1, wv[1][o], fmaf(e2, wv[2][o], e3 * wv[3][o])));
    }
}

extern "C" void kernel_launch(void* const* d_in, const int* in_sizes, int n_in,
                              void* d_out, int out_size, void* d_ws, size_t ws_size,
                              hipStream_t stream) {
    const float* x     = (const float*)d_in[0];
    const float* emit  = (const float*)d_in[1];
    const float* trans = (const float*)d_in[2];
    const float* initl = (const float*)d_in[3];
    const float* w     = (const float*)d_in[4];
    float* out = (float*)d_out;

    float* le    = (float*)d_ws;                                   // 16 MB
    float* alpha = (float*)((char*)d_ws + (size_t)TDIM * BDIM * SDIM * 4); // 16 MB

    // Kernel A: one thread per (b,t)
    int totA = BDIM * TDIM;
    hipLaunchKernelGGL(le_kernel, dim3(totA / 256), dim3(256), 0, stream, x, emit, le);
    // Kernel B: forward, one thread per b
    hipLaunchKernelGGL(fwd_kernel, dim3(BDIM / 64), dim3(64), 0, stream, le, trans, initl, alpha);
    // Kernel C: backward + output
    hipLaunchKernelGGL(bwd_kernel, dim3(BDIM / 64), dim3(64), 0, stream, le, alpha, trans, w, out);
}

// Round 2
// 165.901 us; speedup vs baseline: 15.0540x; 15.0540x over previous
//
#include <hip/hip_runtime.h>

#define TDIM 4096
#define BDIM 256
#define ADIM 26
#define SDIM 4
#define L_CHUNK 64
#define C_CHUNK 64
#define NEGF -1e30f

__device__ __forceinline__ float lse2f(float a, float b) {
    float m = fmaxf(a, b);
    return m + __logf(__expf(a - m) + __expf(b - m));
}
__device__ __forceinline__ float lse3f(float a, float b, float c) {
    float m = fmaxf(fmaxf(a, b), c);
    return m + __logf(__expf(a - m) + __expf(b - m) + __expf(c - m));
}
__device__ __forceinline__ float lse4f(float a, float b, float c, float d) {
    float m = fmaxf(fmaxf(a, b), fmaxf(c, d));
    return m + __logf(__expf(a - m) + __expf(b - m) + __expf(c - m) + __expf(d - m));
}

struct TransA {
    float A00, A01, A02, A11, A12, A13, A22, A23, A33;
};
__device__ __forceinline__ TransA make_transA(const float* __restrict__ trans) {
    TransA A;
    {
        float l0 = trans[0], l1 = trans[1], l2 = trans[2];
        float m = fmaxf(fmaxf(l0, l1), l2);
        float lz = m + __logf(__expf(l0 - m) + __expf(l1 - m) + __expf(l2 - m));
        A.A00 = l0 - lz; A.A01 = l1 - lz; A.A02 = l2 - lz;
    }
    {
        float l1 = trans[5], l2 = trans[6], l3 = trans[7];
        float m = fmaxf(fmaxf(l1, l2), l3);
        float lz = m + __logf(__expf(l1 - m) + __expf(l2 - m) + __expf(l3 - m));
        A.A11 = l1 - lz; A.A12 = l2 - lz; A.A13 = l3 - lz;
    }
    {
        float l2 = trans[10], l3 = trans[11];
        float m = fmaxf(l2, l3);
        float lz = m + __logf(__expf(l2 - m) + __expf(l3 - m));
        A.A22 = l2 - lz; A.A23 = l3 - lz;
    }
    A.A33 = 0.f;
    return A;
}

// ---------------- Kernel A: log_emit ----------------
__global__ void le_kernel(const float* __restrict__ x,
                          const float* __restrict__ emit,
                          float* __restrict__ le) {
    __shared__ float Bmat[SDIM][ADIM];
    int tid = threadIdx.x;
    if (tid < SDIM) {
        float m = -1e30f;
        #pragma unroll
        for (int a = 0; a < ADIM; ++a) m = fmaxf(m, emit[tid * ADIM + a]);
        float tmp[ADIM];
        float z = 0.f;
        #pragma unroll
        for (int a = 0; a < ADIM; ++a) {
            float e = __expf(emit[tid * ADIM + a] - m);
            tmp[a] = e;
            z += e;
        }
        float inv = 1.f / z;
        #pragma unroll
        for (int a = 0; a < ADIM; ++a) Bmat[tid][a] = tmp[a] * inv;
    }
    __syncthreads();

    int idx = blockIdx.x * blockDim.x + tid;   // 0 .. B*T-1
    int b = idx >> 12;
    int t = idx & (TDIM - 1);

    const float* xp = x + (size_t)idx * ADIM;
    float v[ADIM];
    #pragma unroll
    for (int a = 0; a < ADIM; a += 2) {
        float2 u = *reinterpret_cast<const float2*>(xp + a);
        v[a] = u.x; v[a + 1] = u.y;
    }
    float m = v[0];
    #pragma unroll
    for (int a = 1; a < ADIM; ++a) m = fmaxf(m, v[a]);
    float z = 0.f, d0 = 0.f, d1 = 0.f, d2 = 0.f, d3 = 0.f;
    #pragma unroll
    for (int a = 0; a < ADIM; ++a) {
        float e = __expf(v[a] - m);
        z += e;
        d0 = fmaf(e, Bmat[0][a], d0);
        d1 = fmaf(e, Bmat[1][a], d1);
        d2 = fmaf(e, Bmat[2][a], d2);
        d3 = fmaf(e, Bmat[3][a], d3);
    }
    float invz = 1.f / z;
    float4 r;
    r.x = __logf(fmaf(d0, invz, 1e-16f));
    r.y = __logf(fmaf(d1, invz, 1e-16f));
    r.z = __logf(fmaf(d2, invz, 1e-16f));
    r.w = __logf(fmaf(d3, invz, 1e-16f));
    *reinterpret_cast<float4*>(le + ((size_t)t * BDIM + b) * SDIM) = r;
}

// Upper-triangular log-semiring matrix step: M <- (M o A) + diag-emission e
// Row-wise: M_new[i][j] = LSE_k(M[i][k] + A[k][j]) + e_j  (A upper-tri, A33=0)
#define FSTEP(E) do { \
    float e0_ = (E).x, e1_ = (E).y, e2_ = (E).z, e3_ = (E).w; \
    float n00 = M00 + A.A00 + e0_; \
    float n01 = lse2f(M00 + A.A01, M01 + A.A11) + e1_; \
    float n02 = lse3f(M00 + A.A02, M01 + A.A12, M02 + A.A22) + e2_; \
    float n03 = lse3f(M01 + A.A13, M02 + A.A23, M03) + e3_; \
    float n11 = M11 + A.A11 + e1_; \
    float n12 = lse2f(M11 + A.A12, M12 + A.A22) + e2_; \
    float n13 = lse3f(M11 + A.A13, M12 + A.A23, M13) + e3_; \
    float n22 = M22 + A.A22 + e2_; \
    float n23 = lse2f(M22 + A.A23, M23) + e3_; \
    float n33 = M33 + e3_; \
    M00 = n00; M01 = n01; M02 = n02; M03 = n03; \
    M11 = n11; M12 = n12; M13 = n13; M22 = n22; M23 = n23; M33 = n33; \
} while (0)

// Vector alpha step with renormalization
#define ASTEP(E) do { \
    float n0_ = a0 + A.A00; \
    float n1_ = lse2f(a0 + A.A01, a1 + A.A11); \
    float n2_ = lse3f(a0 + A.A02, a1 + A.A12, a2 + A.A22); \
    float n3_ = lse3f(a1 + A.A13, a2 + A.A23, a3); \
    a0 = n0_ + (E).x; a1 = n1_ + (E).y; a2 = n2_ + (E).z; a3 = n3_ + (E).w; \
    float mm_ = fmaxf(fmaxf(a0, a1), fmaxf(a2, a3)); \
    a0 -= mm_; a1 -= mm_; a2 -= mm_; a3 -= mm_; \
} while (0)

// Vector beta step with renormalization
#define BSTEP(E) do { \
    float f0_ = (E).x + b0, f1_ = (E).y + b1, f2_ = (E).z + b2, f3_ = (E).w + b3; \
    float n0_ = lse3f(A.A00 + f0_, A.A01 + f1_, A.A02 + f2_); \
    float n1_ = lse3f(A.A11 + f1_, A.A12 + f2_, A.A13 + f3_); \
    float n2_ = lse2f(A.A22 + f2_, A.A23 + f3_); \
    float n3_ = f3_; \
    float bm_ = fmaxf(fmaxf(n0_, n1_), fmaxf(n2_, n3_)); \
    b0 = n0_ - bm_; b1 = n1_ - bm_; b2 = n2_ - bm_; b3 = n3_ - bm_; \
} while (0)

// gamma = softmax(alpha+beta); out = gamma . w
#define EMIT(AV, TIDX) do { \
    float g0_ = (AV).x + b0, g1_ = (AV).y + b1, g2_ = (AV).z + b2, g3_ = (AV).w + b3; \
    float gm_ = fmaxf(fmaxf(g0_, g1_), fmaxf(g2_, g3_)); \
    float q0_ = __expf(g0_ - gm_), q1_ = __expf(g1_ - gm_); \
    float q2_ = __expf(g2_ - gm_), q3_ = __expf(g3_ - gm_); \
    float inv_ = 1.f / (q0_ + q1_ + q2_ + q3_); \
    q0_ *= inv_; q1_ *= inv_; q2_ *= inv_; q3_ *= inv_; \
    float* o_ = op + (size_t)(TIDX) * 5; \
    o_[0] = fmaf(q0_, wv[0][0], fmaf(q1_, wv[1][0], fmaf(q2_, wv[2][0], q3_ * wv[3][0]))); \
    o_[1] = fmaf(q0_, wv[0][1], fmaf(q1_, wv[1][1], fmaf(q2_, wv[2][1], q3_ * wv[3][1]))); \
    o_[2] = fmaf(q0_, wv[0][2], fmaf(q1_, wv[1][2], fmaf(q2_, wv[2][2], q3_ * wv[3][2]))); \
    o_[3] = fmaf(q0_, wv[0][3], fmaf(q1_, wv[1][3], fmaf(q2_, wv[2][3], q3_ * wv[3][3]))); \
    o_[4] = fmaf(q0_, wv[0][4], fmaf(q1_, wv[1][4], fmaf(q2_, wv[2][4], q3_ * wv[3][4]))); \
} while (0)

// ---------------- pass 1 forward: chunk operator M_c ----------------
// M_c maps alpha_{c*L-1} -> alpha_{(c+1)*L-1}; chunk0 uses identity "transition" at t=0.
__global__ __launch_bounds__(64) void p1f_kernel(const float* __restrict__ le,
                                                 const float* __restrict__ trans,
                                                 float* __restrict__ Mbuf) {
    int bb = blockIdx.x * 64 + threadIdx.x;
    int c = blockIdx.y;
    TransA A = make_transA(trans);
    const float4* lep = reinterpret_cast<const float4*>(le) + bb;
    int t0 = c * L_CHUNK;

    float4 buf[8], nb[8];
    #pragma unroll
    for (int k = 0; k < 8; ++k) buf[k] = lep[(size_t)(t0 + k) * BDIM];
    #pragma unroll
    for (int k = 0; k < 8; ++k) nb[k] = lep[(size_t)(t0 + 8 + k) * BDIM];

    float M00, M01, M02, M03, M11, M12, M13, M22, M23, M33;
    float4 e0v = buf[0];
    if (c == 0) {
        M00 = e0v.x; M11 = e0v.y; M22 = e0v.z; M33 = e0v.w;
        M01 = NEGF; M02 = NEGF; M03 = NEGF; M12 = NEGF; M13 = NEGF; M23 = NEGF;
    } else {
        M00 = A.A00 + e0v.x; M01 = A.A01 + e0v.y; M02 = A.A02 + e0v.z; M03 = NEGF;
        M11 = A.A11 + e0v.y; M12 = A.A12 + e0v.z; M13 = A.A13 + e0v.w;
        M22 = A.A22 + e0v.z; M23 = A.A23 + e0v.w; M33 = e0v.w;  // A33=0
    }
    #pragma unroll
    for (int k = 1; k < 8; ++k) FSTEP(buf[k]);
    for (int sb = 1; sb < 8; ++sb) {
        #pragma unroll
        for (int k = 0; k < 8; ++k) buf[k] = nb[k];
        if (sb < 7) {
            #pragma unroll
            for (int k = 0; k < 8; ++k) nb[k] = lep[(size_t)(t0 + (sb + 1) * 8 + k) * BDIM];
        }
        #pragma unroll
        for (int k = 0; k < 8; ++k) FSTEP(buf[k]);
    }
    float* Mb = Mbuf + (size_t)c * 10 * BDIM + bb;
    Mb[0 * BDIM] = M00; Mb[1 * BDIM] = M01; Mb[2 * BDIM] = M02; Mb[3 * BDIM] = M03;
    Mb[4 * BDIM] = M11; Mb[5 * BDIM] = M12; Mb[6 * BDIM] = M13;
    Mb[7 * BDIM] = M22; Mb[8 * BDIM] = M23; Mb[9 * BDIM] = M33;
}

// ---------------- pass 1 backward: chunk operator N_c (built ascending) ----------------
// N_c maps beta_{(c+1)*L} -> beta_{c*L}  (last chunk: beta_{T-1} -> beta_{c*L})
__global__ __launch_bounds__(64) void p1b_kernel(const float* __restrict__ le,
                                                 const float* __restrict__ trans,
                                                 float* __restrict__ Nbuf) {
    int bb = blockIdx.x * 64 + threadIdx.x;
    int c = blockIdx.y;
    TransA A = make_transA(trans);
    const float4* lep = reinterpret_cast<const float4*>(le) + bb;
    int t0 = c * L_CHUNK;
    int jmax = (c == C_CHUNK - 1) ? (TDIM - 1) : (t0 + L_CHUNK);

    float M00 = 0.f, M11 = 0.f, M22 = 0.f, M33 = 0.f;
    float M01 = NEGF, M02 = NEGF, M03 = NEGF, M12 = NEGF, M13 = NEGF, M23 = NEGF;

    float4 buf[8], nb[8];
    #pragma unroll
    for (int k = 0; k < 8; ++k) { int j = min(t0 + 1 + k, TDIM - 1); buf[k] = lep[(size_t)j * BDIM]; }
    #pragma unroll
    for (int k = 0; k < 8; ++k) { int j = min(t0 + 9 + k, TDIM - 1); nb[k] = lep[(size_t)j * BDIM]; }

    for (int sb = 0; sb < 8; ++sb) {
        if (sb > 0) {
            #pragma unroll
            for (int k = 0; k < 8; ++k) buf[k] = nb[k];
            if (sb < 7) {
                #pragma unroll
                for (int k = 0; k < 8; ++k) {
                    int j = min(t0 + 1 + (sb + 1) * 8 + k, TDIM - 1);
                    nb[k] = lep[(size_t)j * BDIM];
                }
            }
        }
        #pragma unroll
        for (int k = 0; k < 8; ++k) {
            if (t0 + 1 + sb * 8 + k <= jmax) FSTEP(buf[k]);
        }
    }
    float* Nb = Nbuf + (size_t)c * 10 * BDIM + bb;
    Nb[0 * BDIM] = M00; Nb[1 * BDIM] = M01; Nb[2 * BDIM] = M02; Nb[3 * BDIM] = M03;
    Nb[4 * BDIM] = M11; Nb[5 * BDIM] = M12; Nb[6 * BDIM] = M13;
    Nb[7 * BDIM] = M22; Nb[8 * BDIM] = M23; Nb[9 * BDIM] = M33;
}

// ---------------- scan forward over chunk operators ----------------
__global__ __launch_bounds__(64) void scanf_kernel(const float* __restrict__ Mbuf,
                                                   const float* __restrict__ initl,
                                                   float* __restrict__ vin) {
    int bb = blockIdx.x * 64 + threadIdx.x;
    float v0, v1, v2, v3;
    {
        float i0 = initl[0], i1 = initl[1], i2 = initl[2], i3 = initl[3];
        float m = fmaxf(fmaxf(i0, i1), fmaxf(i2, i3));
        float lz = m + __logf(__expf(i0 - m) + __expf(i1 - m) + __expf(i2 - m) + __expf(i3 - m));
        v0 = i0 - lz; v1 = i1 - lz; v2 = i2 - lz; v3 = i3 - lz;
    }
    float cur[10], nxt[10];
    #pragma unroll
    for (int k = 0; k < 10; ++k) nxt[k] = Mbuf[(size_t)k * BDIM + bb];
    for (int c = 0; c < C_CHUNK; ++c) {
        #pragma unroll
        for (int k = 0; k < 10; ++k) cur[k] = nxt[k];
        if (c + 1 < C_CHUNK) {
            #pragma unroll
            for (int k = 0; k < 10; ++k) nxt[k] = Mbuf[((size_t)(c + 1) * 10 + k) * BDIM + bb];
        }
        vin[((size_t)c * 4 + 0) * BDIM + bb] = v0;
        vin[((size_t)c * 4 + 1) * BDIM + bb] = v1;
        vin[((size_t)c * 4 + 2) * BDIM + bb] = v2;
        vin[((size_t)c * 4 + 3) * BDIM + bb] = v3;
        float n0 = v0 + cur[0];
        float n1 = lse2f(v0 + cur[1], v1 + cur[4]);
        float n2 = lse3f(v0 + cur[2], v1 + cur[5], v2 + cur[7]);
        float n3 = lse4f(v0 + cur[3], v1 + cur[6], v2 + cur[8], v3 + cur[9]);
        float mm = fmaxf(fmaxf(n0, n1), fmaxf(n2, n3));
        v0 = n0 - mm; v1 = n1 - mm; v2 = n2 - mm; v3 = n3 - mm;
    }
}

// ---------------- scan backward over chunk operators ----------------
__global__ __launch_bounds__(64) void scanb_kernel(const float* __restrict__ Nbuf,
                                                   float* __restrict__ wbuf) {
    int bb = blockIdx.x * 64 + threadIdx.x;
    float u0 = 0.f, u1 = 0.f, u2 = 0.f, u3 = 0.f;
    float cur[10], nxt[10];
    #pragma unroll
    for (int k = 0; k < 10; ++k) nxt[k] = Nbuf[((size_t)(C_CHUNK - 1) * 10 + k) * BDIM + bb];
    for (int c = C_CHUNK - 1; c >= 0; --c) {
        #pragma unroll
        for (int k = 0; k < 10; ++k) cur[k] = nxt[k];
        if (c > 0) {
            #pragma unroll
            for (int k = 0; k < 10; ++k) nxt[k] = Nbuf[((size_t)(c - 1) * 10 + k) * BDIM + bb];
        }
        wbuf[((size_t)c * 4 + 0) * BDIM + bb] = u0;
        wbuf[((size_t)c * 4 + 1) * BDIM + bb] = u1;
        wbuf[((size_t)c * 4 + 2) * BDIM + bb] = u2;
        wbuf[((size_t)c * 4 + 3) * BDIM + bb] = u3;
        float n0 = lse4f(cur[0] + u0, cur[1] + u1, cur[2] + u2, cur[3] + u3);
        float n1 = lse3f(cur[4] + u1, cur[5] + u2, cur[6] + u3);
        float n2 = lse2f(cur[7] + u2, cur[8] + u3);
        float n3 = cur[9] + u3;
        float mm = fmaxf(fmaxf(n0, n1), fmaxf(n2, n3));
        u0 = n0 - mm; u1 = n1 - mm; u2 = n2 - mm; u3 = n3 - mm;
    }
}

// ---------------- pass 2 forward: materialize normalized alpha ----------------
__global__ __launch_bounds__(64) void p2f_kernel(const float* __restrict__ le,
                                                 const float* __restrict__ vin,
                                                 const float* __restrict__ trans,
                                                 float* __restrict__ alpha) {
    int bb = blockIdx.x * 64 + threadIdx.x;
    int c = blockIdx.y;
    TransA A = make_transA(trans);
    const float4* lep = reinterpret_cast<const float4*>(le) + bb;
    float4* ap = reinterpret_cast<float4*>(alpha) + bb;
    int t0 = c * L_CHUNK;

    float a0 = vin[((size_t)c * 4 + 0) * BDIM + bb];
    float a1 = vin[((size_t)c * 4 + 1) * BDIM + bb];
    float a2 = vin[((size_t)c * 4 + 2) * BDIM + bb];
    float a3 = vin[((size_t)c * 4 + 3) * BDIM + bb];

    float4 buf[8], nb[8];
    #pragma unroll
    for (int k = 0; k < 8; ++k) buf[k] = lep[(size_t)(t0 + k) * BDIM];
    #pragma unroll
    for (int k = 0; k < 8; ++k) nb[k] = lep[(size_t)(t0 + 8 + k) * BDIM];

    if (c == 0) {   // alpha_0 = log_pi + e_0 (identity "transition")
        a0 += buf[0].x; a1 += buf[0].y; a2 += buf[0].z; a3 += buf[0].w;
        float mm = fmaxf(fmaxf(a0, a1), fmaxf(a2, a3));
        a0 -= mm; a1 -= mm; a2 -= mm; a3 -= mm;
    } else {
        ASTEP(buf[0]);
    }
    ap[(size_t)t0 * BDIM] = make_float4(a0, a1, a2, a3);
    #pragma unroll
    for (int k = 1; k < 8; ++k) {
        ASTEP(buf[k]);
        ap[(size_t)(t0 + k) * BDIM] = make_float4(a0, a1, a2, a3);
    }
    for (int sb = 1; sb < 8; ++sb) {
        #pragma unroll
        for (int k = 0; k < 8; ++k) buf[k] = nb[k];
        if (sb < 7) {
            #pragma unroll
            for (int k = 0; k < 8; ++k) nb[k] = lep[(size_t)(t0 + (sb + 1) * 8 + k) * BDIM];
        }
        #pragma unroll
        for (int k = 0; k < 8; ++k) {
            ASTEP(buf[k]);
            ap[(size_t)(t0 + sb * 8 + k) * BDIM] = make_float4(a0, a1, a2, a3);
        }
    }
}

// ---------------- final: beta replay + gamma + output ----------------
__global__ __launch_bounds__(64) void final_kernel(const float* __restrict__ le,
                                                   const float* __restrict__ alpha,
                                                   const float* __restrict__ wbuf,
                                                   const float* __restrict__ trans,
                                                   const float* __restrict__ w,
                                                   float* __restrict__ out) {
    int bb = blockIdx.x * 64 + threadIdx.x;
    int c = blockIdx.y;
    TransA A = make_transA(trans);
    float wv[SDIM][5];
    #pragma unroll
    for (int s = 0; s < SDIM; ++s)
        #pragma unroll
        for (int o = 0; o < 5; ++o) wv[s][o] = w[s * 5 + o];

    const float4* lep = reinterpret_cast<const float4*>(le) + bb;
    const float4* app = reinterpret_cast<const float4*>(alpha) + bb;
    float* op = out + (size_t)bb * TDIM * 5;
    int t0 = c * L_CHUNK;

    float b0 = wbuf[((size_t)c * 4 + 0) * BDIM + bb];
    float b1 = wbuf[((size_t)c * 4 + 1) * BDIM + bb];
    float b2 = wbuf[((size_t)c * 4 + 2) * BDIM + bb];
    float b3 = wbuf[((size_t)c * 4 + 3) * BDIM + bb];

    int tstart, nsteps;
    if (c == C_CHUNK - 1) {
        float4 av = app[(size_t)(TDIM - 1) * BDIM];
        EMIT(av, TDIM - 1);
        tstart = TDIM - 2; nsteps = L_CHUNK - 1;
    } else {
        tstart = t0 + L_CHUNK - 1; nsteps = L_CHUNK;
    }

    float4 eb[4], ab[4], en[4], an[4];
    #pragma unroll
    for (int k = 0; k < 4; ++k) {
        int t = tstart - k;
        eb[k] = lep[(size_t)(t + 1) * BDIM];
        ab[k] = app[(size_t)t * BDIM];
    }
    #pragma unroll
    for (int k = 0; k < 4; ++k) {
        int t = tstart - 4 - k; int tc = t < 0 ? 0 : t;
        en[k] = lep[(size_t)(tc + 1) * BDIM];
        an[k] = app[(size_t)tc * BDIM];
    }
    for (int sb = 0; sb < 16; ++sb) {
        if (sb > 0) {
            #pragma unroll
            for (int k = 0; k < 4; ++k) { eb[k] = en[k]; ab[k] = an[k]; }
            if (sb < 15) {
                #pragma unroll
                for (int k = 0; k < 4; ++k) {
                    int t = tstart - (sb + 1) * 4 - k; int tc = t < 0 ? 0 : t;
                    en[k] = lep[(size_t)(tc + 1) * BDIM];
                    an[k] = app[(size_t)tc * BDIM];
                }
            }
        }
        #pragma unroll
        for (int k = 0; k < 4; ++k) {
            int m = sb * 4 + k;
            if (m < nsteps) {
                BSTEP(eb[k]);
                EMIT(ab[k], tstart - m);
            }
        }
    }
}

// ================= fallback path (round-1 kernels, needs only 32MB ws) =================
__global__ void fwd_kernel(const float* __restrict__ le,
                           const float* __restrict__ trans,
                           const float* __restrict__ initl,
                           float* __restrict__ alpha) {
    int bb = blockIdx.x * blockDim.x + threadIdx.x;
    TransA A = make_transA(trans);
    float a0, a1, a2, a3;
    {
        float i0 = initl[0], i1 = initl[1], i2 = initl[2], i3 = initl[3];
        float m = fmaxf(fmaxf(i0, i1), fmaxf(i2, i3));
        float lz = m + __logf(__expf(i0 - m) + __expf(i1 - m) + __expf(i2 - m) + __expf(i3 - m));
        a0 = i0 - lz; a1 = i1 - lz; a2 = i2 - lz; a3 = i3 - lz;
    }
    const float4* lep = reinterpret_cast<const float4*>(le) + bb;
    float4* ap = reinterpret_cast<float4*>(alpha) + bb;

    float4 e = lep[0];
    a0 += e.x; a1 += e.y; a2 += e.z; a3 += e.w;
    float mm = fmaxf(fmaxf(a0, a1), fmaxf(a2, a3));
    a0 -= mm; a1 -= mm; a2 -= mm; a3 -= mm;
    ap[0] = make_float4(a0, a1, a2, a3);

    float4 en = lep[BDIM];
    for (int t = 1; t < TDIM; ++t) {
        float4 cur = en;
        if (t + 1 < TDIM) en = lep[(size_t)(t + 1) * BDIM];
        ASTEP(cur);
        ap[(size_t)t * BDIM] = make_float4(a0, a1, a2, a3);
    }
}

__global__ void bwd_kernel(const float* __restrict__ le,
                           const float* __restrict__ alpha,
                           const float* __restrict__ trans,
                           const float* __restrict__ w,
                           float* __restrict__ out) {
    int bb = blockIdx.x * blockDim.x + threadIdx.x;
    TransA A = make_transA(trans);
    float wv[SDIM][5];
    #pragma unroll
    for (int s = 0; s < SDIM; ++s)
        #pragma unroll
        for (int o = 0; o < 5; ++o) wv[s][o] = w[s * 5 + o];

    const float4* lep = reinterpret_cast<const float4*>(le) + bb;
    const float4* app = reinterpret_cast<const float4*>(alpha) + bb;
    float* op = out + (size_t)bb * TDIM * 5;

    float b0 = 0.f, b1 = 0.f, b2 = 0.f, b3 = 0.f;
    {
        float4 av = app[(size_t)(TDIM - 1) * BDIM];
        EMIT(av, TDIM - 1);
    }
    float4 e = lep[(size_t)(TDIM - 1) * BDIM];
    float4 av = app[(size_t)(TDIM - 2) * BDIM];
    for (int t = TDIM - 2; t >= 0; --t) {
        float4 ecur = e;
        float4 acur = av;
        if (t > 0) {
            e = lep[(size_t)t * BDIM];
            av = app[(size_t)(t - 1) * BDIM];
        }
        BSTEP(ecur);
        EMIT(acur, t);
    }
}

extern "C" void kernel_launch(void* const* d_in, const int* in_sizes, int n_in,
                              void* d_out, int out_size, void* d_ws, size_t ws_size,
                              hipStream_t stream) {
    const float* x     = (const float*)d_in[0];
    const float* emit  = (const float*)d_in[1];
    const float* trans = (const float*)d_in[2];
    const float* initl = (const float*)d_in[3];
    const float* w     = (const float*)d_in[4];
    float* out = (float*)d_out;

    const size_t LE_BYTES = (size_t)TDIM * BDIM * SDIM * 4;   // 16 MB
    float* le    = (float*)d_ws;
    float* alpha = (float*)((char*)d_ws + LE_BYTES);

    const size_t MB_BYTES  = (size_t)C_CHUNK * 10 * BDIM * 4; // 640 KB
    const size_t VB_BYTES  = (size_t)C_CHUNK * 4 * BDIM * 4;  // 256 KB
    const size_t M_OFF   = 2 * LE_BYTES;
    const size_t N_OFF   = M_OFF + MB_BYTES;
    const size_t VIN_OFF = N_OFF + MB_BYTES;
    const size_t WB_OFF  = VIN_OFF + VB_BYTES;
    const size_t NEEDED  = WB_OFF + VB_BYTES;

    hipLaunchKernelGGL(le_kernel, dim3(BDIM * TDIM / 256), dim3(256), 0, stream, x, emit, le);

    if (ws_size >= NEEDED) {
        float* Mbuf = (float*)((char*)d_ws + M_OFF);
        float* Nbuf = (float*)((char*)d_ws + N_OFF);
        float* vin  = (float*)((char*)d_ws + VIN_OFF);
        float* wb   = (float*)((char*)d_ws + WB_OFF);

        dim3 pgrid(BDIM / 64, C_CHUNK);
        hipLaunchKernelGGL(p1f_kernel, pgrid, dim3(64), 0, stream, le, trans, Mbuf);
        hipLaunchKernelGGL(p1b_kernel, pgrid, dim3(64), 0, stream, le, trans, Nbuf);
        hipLaunchKernelGGL(scanf_kernel, dim3(BDIM / 64), dim3(64), 0, stream, Mbuf, initl, vin);
        hipLaunchKernelGGL(scanb_kernel, dim3(BDIM / 64), dim3(64), 0, stream, Nbuf, wb);
        hipLaunchKernelGGL(p2f_kernel, pgrid, dim3(64), 0, stream, le, vin, trans, alpha);
        hipLaunchKernelGGL(final_kernel, pgrid, dim3(64), 0, stream, le, alpha, wb, trans, w, out);
    } else {
        hipLaunchKernelGGL(fwd_kernel, dim3(BDIM / 64), dim3(64), 0, stream, le, trans, initl, alpha);
        hipLaunchKernelGGL(bwd_kernel, dim3(BDIM / 64), dim3(64), 0, stream, le, alpha, trans, w, out);
    }
}

// Round 4
// 101.756 us; speedup vs baseline: 24.5438x; 1.6304x over previous
//
#include <hip/hip_runtime.h>

#define TDIM 4096
#define BDIM 256
#define ADIM 26
#define SDIM 4
#define L_CHUNK 32
#define C_CHUNK 128
#define NEGF -1e30f
#define LOG2E 1.44269504088896340736f

// log2-domain LSE helpers (exp2f/log2 are the raw HW transcendentals; no __exp2f in HIP)
__device__ __forceinline__ float l2se2(float a, float b) {
    float m = fmaxf(a, b);
    return m + __log2f(exp2f(a - m) + exp2f(b - m));
}
__device__ __forceinline__ float l2se3(float a, float b, float c) {
    float m = fmaxf(fmaxf(a, b), c);
    return m + __log2f(exp2f(a - m) + exp2f(b - m) + exp2f(c - m));
}
__device__ __forceinline__ float l2se4(float a, float b, float c, float d) {
    float m = fmaxf(fmaxf(a, b), fmaxf(c, d));
    return m + __log2f(exp2f(a - m) + exp2f(b - m) + exp2f(c - m) + exp2f(d - m));
}

struct TransA { float A00, A01, A02, A11, A12, A13, A22, A23, A33; };

// masked log-softmax of transition logits, in log2 units
__device__ __forceinline__ TransA make_transA(const float* __restrict__ trans) {
    TransA A;
    {
        float l0 = trans[0], l1 = trans[1], l2 = trans[2];
        float m = fmaxf(fmaxf(l0, l1), l2);
        float lz = m + __logf(__expf(l0 - m) + __expf(l1 - m) + __expf(l2 - m));
        A.A00 = (l0 - lz) * LOG2E; A.A01 = (l1 - lz) * LOG2E; A.A02 = (l2 - lz) * LOG2E;
    }
    {
        float l1 = trans[5], l2 = trans[6], l3 = trans[7];
        float m = fmaxf(fmaxf(l1, l2), l3);
        float lz = m + __logf(__expf(l1 - m) + __expf(l2 - m) + __expf(l3 - m));
        A.A11 = (l1 - lz) * LOG2E; A.A12 = (l2 - lz) * LOG2E; A.A13 = (l3 - lz) * LOG2E;
    }
    {
        float l2 = trans[10], l3 = trans[11];
        float m = fmaxf(l2, l3);
        float lz = m + __logf(__expf(l2 - m) + __expf(l3 - m));
        A.A22 = (l2 - lz) * LOG2E; A.A23 = (l3 - lz) * LOG2E;
    }
    A.A33 = 0.f;
    return A;
}

// ---------------- Kernel A: log_emit (log2 units) ----------------
__global__ void le_kernel(const float* __restrict__ x,
                          const float* __restrict__ emit,
                          float* __restrict__ le) {
    __shared__ float Bmat[SDIM][ADIM];
    int tid = threadIdx.x;
    if (tid < SDIM) {
        float m = -1e30f;
        #pragma unroll
        for (int a = 0; a < ADIM; ++a) m = fmaxf(m, emit[tid * ADIM + a]);
        float tmp[ADIM];
        float z = 0.f;
        #pragma unroll
        for (int a = 0; a < ADIM; ++a) {
            float e = __expf(emit[tid * ADIM + a] - m);
            tmp[a] = e; z += e;
        }
        float inv = 1.f / z;
        #pragma unroll
        for (int a = 0; a < ADIM; ++a) Bmat[tid][a] = tmp[a] * inv;
    }
    __syncthreads();

    int idx = blockIdx.x * blockDim.x + tid;
    int b = idx >> 12;
    int t = idx & (TDIM - 1);

    const float* xp = x + (size_t)idx * ADIM;
    float v[ADIM];
    #pragma unroll
    for (int a = 0; a < ADIM; a += 2) {
        float2 u = *reinterpret_cast<const float2*>(xp + a);
        v[a] = u.x; v[a + 1] = u.y;
    }
    float m = v[0];
    #pragma unroll
    for (int a = 1; a < ADIM; ++a) m = fmaxf(m, v[a]);
    float z = 0.f, d0 = 0.f, d1 = 0.f, d2 = 0.f, d3 = 0.f;
    #pragma unroll
    for (int a = 0; a < ADIM; ++a) {
        float e = __expf(v[a] - m);
        z += e;
        d0 = fmaf(e, Bmat[0][a], d0);
        d1 = fmaf(e, Bmat[1][a], d1);
        d2 = fmaf(e, Bmat[2][a], d2);
        d3 = fmaf(e, Bmat[3][a], d3);
    }
    float invz = 1.f / z;
    float4 r;
    r.x = __log2f(fmaf(d0, invz, 1e-16f));
    r.y = __log2f(fmaf(d1, invz, 1e-16f));
    r.z = __log2f(fmaf(d2, invz, 1e-16f));
    r.w = __log2f(fmaf(d3, invz, 1e-16f));
    *reinterpret_cast<float4*>(le + ((size_t)t * BDIM + b) * SDIM) = r;
}

// upper-triangular chunk operator, 10 live entries
struct UT { float m00, m01, m02, m03, m11, m12, m13, m22, m23, m33; };

__device__ __forceinline__ void fstep(UT& M, const TransA& A, float4 e) {
    float n00 = M.m00 + A.A00 + e.x;
    float n01 = l2se2(M.m00 + A.A01, M.m01 + A.A11) + e.y;
    float n02 = l2se3(M.m00 + A.A02, M.m01 + A.A12, M.m02 + A.A22) + e.z;
    float n03 = l2se3(M.m01 + A.A13, M.m02 + A.A23, M.m03) + e.w;
    float n11 = M.m11 + A.A11 + e.y;
    float n12 = l2se2(M.m11 + A.A12, M.m12 + A.A22) + e.z;
    float n13 = l2se3(M.m11 + A.A13, M.m12 + A.A23, M.m13) + e.w;
    float n22 = M.m22 + A.A22 + e.z;
    float n23 = l2se2(M.m22 + A.A23, M.m23) + e.w;
    float n33 = M.m33 + e.w;
    M.m00 = n00; M.m01 = n01; M.m02 = n02; M.m03 = n03;
    M.m11 = n11; M.m12 = n12; M.m13 = n13; M.m22 = n22; M.m23 = n23; M.m33 = n33;
}

#define ASTEP(E) do { \
    float n0_ = a0 + A.A00; \
    float n1_ = l2se2(a0 + A.A01, a1 + A.A11); \
    float n2_ = l2se3(a0 + A.A02, a1 + A.A12, a2 + A.A22); \
    float n3_ = l2se3(a1 + A.A13, a2 + A.A23, a3); \
    a0 = n0_ + (E).x; a1 = n1_ + (E).y; a2 = n2_ + (E).z; a3 = n3_ + (E).w; \
    float mm_ = fmaxf(fmaxf(a0, a1), fmaxf(a2, a3)); \
    a0 -= mm_; a1 -= mm_; a2 -= mm_; a3 -= mm_; \
} while (0)

#define BSTEP(E) do { \
    float f0_ = (E).x + b0, f1_ = (E).y + b1, f2_ = (E).z + b2, f3_ = (E).w + b3; \
    float n0_ = l2se3(A.A00 + f0_, A.A01 + f1_, A.A02 + f2_); \
    float n1_ = l2se3(A.A11 + f1_, A.A12 + f2_, A.A13 + f3_); \
    float n2_ = l2se2(A.A22 + f2_, A.A23 + f3_); \
    float n3_ = f3_; \
    float bm_ = fmaxf(fmaxf(n0_, n1_), fmaxf(n2_, n3_)); \
    b0 = n0_ - bm_; b1 = n1_ - bm_; b2 = n2_ - bm_; b3 = n3_ - bm_; \
} while (0)

// gamma -> vals[Q*5 .. Q*5+4]
#define GEMIT(AV, Q) do { \
    float g0_ = (AV).x + b0, g1_ = (AV).y + b1, g2_ = (AV).z + b2, g3_ = (AV).w + b3; \
    float gm_ = fmaxf(fmaxf(g0_, g1_), fmaxf(g2_, g3_)); \
    float q0_ = exp2f(g0_ - gm_), q1_ = exp2f(g1_ - gm_); \
    float q2_ = exp2f(g2_ - gm_), q3_ = exp2f(g3_ - gm_); \
    float inv_ = 1.f / (q0_ + q1_ + q2_ + q3_); \
    q0_ *= inv_; q1_ *= inv_; q2_ *= inv_; q3_ *= inv_; \
    vals[(Q)*5 + 0] = fmaf(q0_, wv[0][0], fmaf(q1_, wv[1][0], fmaf(q2_, wv[2][0], q3_ * wv[3][0]))); \
    vals[(Q)*5 + 1] = fmaf(q0_, wv[0][1], fmaf(q1_, wv[1][1], fmaf(q2_, wv[2][1], q3_ * wv[3][1]))); \
    vals[(Q)*5 + 2] = fmaf(q0_, wv[0][2], fmaf(q1_, wv[1][2], fmaf(q2_, wv[2][2], q3_ * wv[3][2]))); \
    vals[(Q)*5 + 3] = fmaf(q0_, wv[0][3], fmaf(q1_, wv[1][3], fmaf(q2_, wv[2][3], q3_ * wv[3][3]))); \
    vals[(Q)*5 + 4] = fmaf(q0_, wv[0][4], fmaf(q1_, wv[1][4], fmaf(q2_, wv[2][4], q3_ * wv[3][4]))); \
} while (0)

// ---------------- pass 1: chunk operators, fwd (z=0) and bwd (z=1) ----------------
// Writes operators in scan-lane layout: buf2[c][j][b] = float4 over k of
//   fwd: M[j^k][j]  (NEGF if j^k > j)   bwd: N[j][j^k]  (NEGF if j^k < j)
__global__ __launch_bounds__(64) void p1_kernel(const float* __restrict__ le,
                                                const float* __restrict__ trans,
                                                float* __restrict__ Mb2,
                                                float* __restrict__ Nb2) {
    int bb = blockIdx.x * 64 + threadIdx.x;
    int c = blockIdx.y;
    bool bz = blockIdx.z != 0;
    TransA A = make_transA(trans);
    const float4* lep = reinterpret_cast<const float4*>(le) + bb;
    int t0 = c * L_CHUNK;
    int base = t0 + (bz ? 1 : 0);

    float4 lb[L_CHUNK];
    #pragma unroll
    for (int k = 0; k < L_CHUNK; ++k) {
        int t = base + k; if (t > TDIM - 1) t = TDIM - 1;
        lb[k] = lep[(size_t)t * BDIM];
    }

    UT M;
    if (!bz) {
        float4 e0 = lb[0];
        if (c == 0) {
            M.m00 = e0.x; M.m11 = e0.y; M.m22 = e0.z; M.m33 = e0.w;
            M.m01 = NEGF; M.m02 = NEGF; M.m03 = NEGF; M.m12 = NEGF; M.m13 = NEGF; M.m23 = NEGF;
        } else {
            M.m00 = A.A00 + e0.x; M.m01 = A.A01 + e0.y; M.m02 = A.A02 + e0.z; M.m03 = NEGF;
            M.m11 = A.A11 + e0.y; M.m12 = A.A12 + e0.z; M.m13 = A.A13 + e0.w;
            M.m22 = A.A22 + e0.z; M.m23 = A.A23 + e0.w; M.m33 = e0.w;
        }
        #pragma unroll
        for (int k = 1; k < L_CHUNK; ++k) fstep(M, A, lb[k]);
        float4* o = reinterpret_cast<float4*>(Mb2) + (size_t)c * 4 * BDIM + bb;
        o[0 * BDIM] = make_float4(M.m00, NEGF,  NEGF,  NEGF );
        o[1 * BDIM] = make_float4(M.m11, M.m01, NEGF,  NEGF );
        o[2 * BDIM] = make_float4(M.m22, NEGF,  M.m02, M.m12);
        o[3 * BDIM] = make_float4(M.m33, M.m23, M.m13, M.m03);
    } else {
        M.m00 = 0.f; M.m11 = 0.f; M.m22 = 0.f; M.m33 = 0.f;
        M.m01 = NEGF; M.m02 = NEGF; M.m03 = NEGF; M.m12 = NEGF; M.m13 = NEGF; M.m23 = NEGF;
        int jmax = (c == C_CHUNK - 1) ? (TDIM - 1) : (t0 + L_CHUNK);
        #pragma unroll
        for (int k = 0; k < L_CHUNK; ++k) {
            if (t0 + 1 + k <= jmax) fstep(M, A, lb[k]);
        }
        float4* o = reinterpret_cast<float4*>(Nb2) + (size_t)c * 4 * BDIM + bb;
        o[0 * BDIM] = make_float4(M.m00, M.m01, M.m02, M.m03);
        o[1 * BDIM] = make_float4(M.m11, NEGF,  M.m13, M.m12);
        o[2 * BDIM] = make_float4(M.m22, M.m23, NEGF,  NEGF );
        o[3 * BDIM] = make_float4(M.m33, NEGF,  NEGF,  NEGF );
    }
}

// ---------------- fused lane-parallel scans ----------------
// 8 lanes per b: lanes 0-3 forward (lane j owns v_j), lanes 4-7 backward (owns u_j).
__global__ __launch_bounds__(64) void scan_kernel(const float* __restrict__ Mb2,
                                                  const float* __restrict__ Nb2,
                                                  const float* __restrict__ initl,
                                                  float* __restrict__ vin,
                                                  float* __restrict__ wbuf) {
    int tid = threadIdx.x;
    int lane = tid & 7;
    int j = lane & 3;
    bool bwd = (lane & 4) != 0;
    int b = blockIdx.x * 8 + (tid >> 3);

    float v;
    if (!bwd) {
        float i0 = initl[0], i1 = initl[1], i2 = initl[2], i3 = initl[3];
        float m = fmaxf(fmaxf(i0, i1), fmaxf(i2, i3));
        float lz = m + __logf(__expf(i0 - m) + __expf(i1 - m) + __expf(i2 - m) + __expf(i3 - m));
        float ij = (j == 0) ? i0 : (j == 1) ? i1 : (j == 2) ? i2 : i3;
        v = (ij - lz) * LOG2E;
    } else {
        v = 0.f;
    }

    const float4* mp = reinterpret_cast<const float4*>(bwd ? Nb2 : Mb2);
    float* op = bwd ? wbuf : vin;

    int c0 = bwd ? (C_CHUNK - 1) : 0;
    int c1 = bwd ? (C_CHUNK - 2) : 1;
    float4 m0 = mp[(size_t)(c0 * 4 + j) * BDIM + b];
    float4 m1 = mp[(size_t)(c1 * 4 + j) * BDIM + b];

    for (int s = 0; s < C_CHUNK; ++s) {
        int c = bwd ? (C_CHUNK - 1 - s) : s;
        float4 mc = m0;
        m0 = m1;
        int s2 = s + 2; if (s2 > C_CHUNK - 1) s2 = C_CHUNK - 1;
        int c2 = bwd ? (C_CHUNK - 1 - s2) : s2;
        m1 = mp[(size_t)(c2 * 4 + j) * BDIM + b];

        op[(size_t)(c * 4 + j) * BDIM + b] = v;   // boundary BEFORE applying op

        float v1 = __shfl_xor(v, 1, 64);
        float v2 = __shfl_xor(v, 2, 64);
        float v3 = __shfl_xor(v1, 2, 64);
        float n = l2se4(v + mc.x, v1 + mc.y, v2 + mc.z, v3 + mc.w);
        float q = fmaxf(n, __shfl_xor(n, 1, 64));
        q = fmaxf(q, __shfl_xor(q, 2, 64));
        v = n - q;
    }
}

// ---------------- pass 2: fwd replay (alpha->LDS) + bwd replay + emit ----------------
__global__ __launch_bounds__(64) void p2_kernel(const float* __restrict__ le,
                                                const float* __restrict__ vin,
                                                const float* __restrict__ wbuf,
                                                const float* __restrict__ trans,
                                                const float* __restrict__ w,
                                                float* __restrict__ out) {
    __shared__ float4 alds[L_CHUNK][64];
    int tid = threadIdx.x;
    int bb = blockIdx.x * 64 + tid;
    int c = blockIdx.y;
    TransA A = make_transA(trans);

    float wv[SDIM][5];
    #pragma unroll
    for (int s = 0; s < SDIM; ++s)
        #pragma unroll
        for (int o = 0; o < 5; ++o) wv[s][o] = w[s * 5 + o];

    const float4* lep = reinterpret_cast<const float4*>(le) + bb;
    int t0 = c * L_CHUNK;

    float4 lb[L_CHUNK];
    #pragma unroll
    for (int k = 0; k < L_CHUNK; ++k) lb[k] = lep[(size_t)(t0 + k) * BDIM];
    int t32 = t0 + L_CHUNK; if (t32 > TDIM - 1) t32 = TDIM - 1;
    float4 e32 = lep[(size_t)t32 * BDIM];

    float a0 = vin[((size_t)c * 4 + 0) * BDIM + bb];
    float a1 = vin[((size_t)c * 4 + 1) * BDIM + bb];
    float a2 = vin[((size_t)c * 4 + 2) * BDIM + bb];
    float a3 = vin[((size_t)c * 4 + 3) * BDIM + bb];

    if (c == 0) {
        a0 += lb[0].x; a1 += lb[0].y; a2 += lb[0].z; a3 += lb[0].w;
        float mm = fmaxf(fmaxf(a0, a1), fmaxf(a2, a3));
        a0 -= mm; a1 -= mm; a2 -= mm; a3 -= mm;
    } else {
        ASTEP(lb[0]);
    }
    alds[0][tid] = make_float4(a0, a1, a2, a3);
    #pragma unroll
    for (int k = 1; k < L_CHUNK; ++k) {
        ASTEP(lb[k]);
        alds[k][tid] = make_float4(a0, a1, a2, a3);
    }

    float b0 = wbuf[((size_t)c * 4 + 0) * BDIM + bb];
    float b1 = wbuf[((size_t)c * 4 + 1) * BDIM + bb];
    float b2 = wbuf[((size_t)c * 4 + 2) * BDIM + bb];
    float b3 = wbuf[((size_t)c * 4 + 3) * BDIM + bb];

    float* op = out + (size_t)bb * TDIM * 5;
    float vals[20];
    bool last = (c == C_CHUNK - 1);

    #pragma unroll
    for (int g = 7; g >= 0; --g) {
        if (last && g == 7) {
            // t = T-1 (beta = 0), then t = T-2 .. T-4
            { float4 av = alds[31][tid]; GEMIT(av, 3); }
            { BSTEP(lb[31]); float4 av = alds[30][tid]; GEMIT(av, 2); }
            { BSTEP(lb[30]); float4 av = alds[29][tid]; GEMIT(av, 1); }
            { BSTEP(lb[29]); float4 av = alds[28][tid]; GEMIT(av, 0); }
        } else {
            #pragma unroll
            for (int q = 3; q >= 0; --q) {
                int idx = g * 4 + q;                        // t = t0 + idx
                float4 e = (idx == 31) ? e32 : lb[idx + 1]; // e_{t+1}
                BSTEP(e);
                float4 av = alds[idx][tid];
                GEMIT(av, q);
            }
        }
        float4* vo = reinterpret_cast<float4*>(op + (size_t)(t0 + g * 4) * 5);
        vo[0] = make_float4(vals[0],  vals[1],  vals[2],  vals[3]);
        vo[1] = make_float4(vals[4],  vals[5],  vals[6],  vals[7]);
        vo[2] = make_float4(vals[8],  vals[9],  vals[10], vals[11]);
        vo[3] = make_float4(vals[12], vals[13], vals[14], vals[15]);
        vo[4] = make_float4(vals[16], vals[17], vals[18], vals[19]);
    }
}

extern "C" void kernel_launch(void* const* d_in, const int* in_sizes, int n_in,
                              void* d_out, int out_size, void* d_ws, size_t ws_size,
                              hipStream_t stream) {
    const float* x     = (const float*)d_in[0];
    const float* emit  = (const float*)d_in[1];
    const float* trans = (const float*)d_in[2];
    const float* initl = (const float*)d_in[3];
    const float* w     = (const float*)d_in[4];
    float* out = (float*)d_out;

    const size_t LE_BYTES = (size_t)TDIM * BDIM * SDIM * 4;          // 16 MB
    const size_t OP_BYTES = (size_t)C_CHUNK * 4 * BDIM * 4 * 4;      // 2 MB (float4 per (c,j,b))
    const size_t VB_BYTES = (size_t)C_CHUNK * 4 * BDIM * 4;          // 512 KB

    char* p = (char*)d_ws;
    float* le   = (float*)p;                 p += LE_BYTES;
    float* Mb2  = (float*)p;                 p += OP_BYTES;
    float* Nb2  = (float*)p;                 p += OP_BYTES;
    float* vin  = (float*)p;                 p += VB_BYTES;
    float* wbuf = (float*)p;

    hipLaunchKernelGGL(le_kernel, dim3(BDIM * TDIM / 256), dim3(256), 0, stream, x, emit, le);
    hipLaunchKernelGGL(p1_kernel, dim3(BDIM / 64, C_CHUNK, 2), dim3(64), 0, stream, le, trans, Mb2, Nb2);
    hipLaunchKernelGGL(scan_kernel, dim3(BDIM * 8 / 64), dim3(64), 0, stream, Mb2, Nb2, initl, vin, wbuf);
    hipLaunchKernelGGL(p2_kernel, dim3(BDIM / 64, C_CHUNK), dim3(64), 0, stream, le, vin, wbuf, trans, w, out);
}

// Round 5
// 84.559 us; speedup vs baseline: 29.5356x; 1.2034x over previous
//
#include <hip/hip_runtime.h>

#define TDIM 4096
#define BDIM 256
#define ADIM 26
#define SDIM 4
#define L_CHUNK 32
#define C_CHUNK 128
#define NEGF -1e30f
#define LOG2E 1.44269504088896340736f

// raw HW transcendentals (single v_exp_f32 / v_log_f32)
__device__ __forceinline__ float ex2(float x) { return __builtin_amdgcn_exp2f(x); }
__device__ __forceinline__ float lg2(float x) { return __builtin_amdgcn_logf(x); }

// log2-domain LSE with max-extraction: one exp2 arg is always 0 -> folded to 1.
__device__ __forceinline__ float l2se2(float a, float b) {
    float mx = fmaxf(a, b), mn = fminf(a, b);
    return mx + lg2(1.f + ex2(mn - mx));
}
__device__ __forceinline__ float l2se3(float a, float b, float c) {
    float mx = fmaxf(fmaxf(a, b), c);
    float md = __builtin_amdgcn_fmed3f(a, b, c);
    float mn = fminf(fminf(a, b), c);
    return mx + lg2(1.f + ex2(md - mx) + ex2(mn - mx));
}
__device__ __forceinline__ float l2se4(float a, float b, float c, float d) {
    float h1 = fmaxf(a, b), l1 = fminf(a, b);
    float h2 = fmaxf(c, d), l2 = fminf(c, d);
    float mx = fmaxf(h1, h2), s2 = fminf(h1, h2);
    return mx + lg2(1.f + ex2(s2 - mx) + ex2(l1 - mx) + ex2(l2 - mx));
}

struct TransA { float A00, A01, A02, A11, A12, A13, A22, A23, A33; };

// masked log-softmax of transition logits, in log2 units
__device__ __forceinline__ TransA make_transA(const float* __restrict__ trans) {
    TransA A;
    {
        float l0 = trans[0], l1 = trans[1], l2 = trans[2];
        float m = fmaxf(fmaxf(l0, l1), l2);
        float lz = m + __logf(__expf(l0 - m) + __expf(l1 - m) + __expf(l2 - m));
        A.A00 = (l0 - lz) * LOG2E; A.A01 = (l1 - lz) * LOG2E; A.A02 = (l2 - lz) * LOG2E;
    }
    {
        float l1 = trans[5], l2 = trans[6], l3 = trans[7];
        float m = fmaxf(fmaxf(l1, l2), l3);
        float lz = m + __logf(__expf(l1 - m) + __expf(l2 - m) + __expf(l3 - m));
        A.A11 = (l1 - lz) * LOG2E; A.A12 = (l2 - lz) * LOG2E; A.A13 = (l3 - lz) * LOG2E;
    }
    {
        float l2 = trans[10], l3 = trans[11];
        float m = fmaxf(l2, l3);
        float lz = m + __logf(__expf(l2 - m) + __expf(l3 - m));
        A.A22 = (l2 - lz) * LOG2E; A.A23 = (l3 - lz) * LOG2E;
    }
    A.A33 = 0.f;
    return A;
}

// ---------------- Kernel A: log_emit (log2 units) ----------------
__global__ void le_kernel(const float* __restrict__ x,
                          const float* __restrict__ emit,
                          float* __restrict__ le) {
    __shared__ float Bmat[SDIM][ADIM];
    int tid = threadIdx.x;
    if (tid < SDIM) {
        float m = -1e30f;
        #pragma unroll
        for (int a = 0; a < ADIM; ++a) m = fmaxf(m, emit[tid * ADIM + a]);
        float tmp[ADIM];
        float z = 0.f;
        #pragma unroll
        for (int a = 0; a < ADIM; ++a) {
            float e = __expf(emit[tid * ADIM + a] - m);
            tmp[a] = e; z += e;
        }
        float inv = 1.f / z;
        #pragma unroll
        for (int a = 0; a < ADIM; ++a) Bmat[tid][a] = tmp[a] * inv;
    }
    __syncthreads();

    int idx = blockIdx.x * blockDim.x + tid;
    int b = idx >> 12;
    int t = idx & (TDIM - 1);

    const float* xp = x + (size_t)idx * ADIM;
    float v[ADIM];
    #pragma unroll
    for (int a = 0; a < ADIM; a += 2) {
        float2 u = *reinterpret_cast<const float2*>(xp + a);
        v[a] = u.x; v[a + 1] = u.y;
    }
    float m = v[0];
    #pragma unroll
    for (int a = 1; a < ADIM; ++a) m = fmaxf(m, v[a]);
    float z = 0.f, d0 = 0.f, d1 = 0.f, d2 = 0.f, d3 = 0.f;
    #pragma unroll
    for (int a = 0; a < ADIM; ++a) {
        float e = ex2((v[a] - m) * LOG2E);
        z += e;
        d0 = fmaf(e, Bmat[0][a], d0);
        d1 = fmaf(e, Bmat[1][a], d1);
        d2 = fmaf(e, Bmat[2][a], d2);
        d3 = fmaf(e, Bmat[3][a], d3);
    }
    float invz = 1.f / z;
    float4 r;
    r.x = lg2(fmaf(d0, invz, 1e-16f));
    r.y = lg2(fmaf(d1, invz, 1e-16f));
    r.z = lg2(fmaf(d2, invz, 1e-16f));
    r.w = lg2(fmaf(d3, invz, 1e-16f));
    *reinterpret_cast<float4*>(le + ((size_t)t * BDIM + b) * SDIM) = r;
}

// upper-triangular chunk operator, 10 live entries
struct UT { float m00, m01, m02, m03, m11, m12, m13, m22, m23, m33; };

__device__ __forceinline__ void fstep(UT& M, const TransA& A, float4 e) {
    float n00 = M.m00 + A.A00 + e.x;
    float n01 = l2se2(M.m00 + A.A01, M.m01 + A.A11) + e.y;
    float n02 = l2se3(M.m00 + A.A02, M.m01 + A.A12, M.m02 + A.A22) + e.z;
    float n03 = l2se3(M.m01 + A.A13, M.m02 + A.A23, M.m03) + e.w;
    float n11 = M.m11 + A.A11 + e.y;
    float n12 = l2se2(M.m11 + A.A12, M.m12 + A.A22) + e.z;
    float n13 = l2se3(M.m11 + A.A13, M.m12 + A.A23, M.m13) + e.w;
    float n22 = M.m22 + A.A22 + e.z;
    float n23 = l2se2(M.m22 + A.A23, M.m23) + e.w;
    float n33 = M.m33 + e.w;
    M.m00 = n00; M.m01 = n01; M.m02 = n02; M.m03 = n03;
    M.m11 = n11; M.m12 = n12; M.m13 = n13; M.m22 = n22; M.m23 = n23; M.m33 = n33;
}

#define ASTEP(E) do { \
    float n0_ = a0 + A.A00; \
    float n1_ = l2se2(a0 + A.A01, a1 + A.A11); \
    float n2_ = l2se3(a0 + A.A02, a1 + A.A12, a2 + A.A22); \
    float n3_ = l2se3(a1 + A.A13, a2 + A.A23, a3); \
    a0 = n0_ + (E).x; a1 = n1_ + (E).y; a2 = n2_ + (E).z; a3 = n3_ + (E).w; \
    float mm_ = fmaxf(fmaxf(a0, a1), fmaxf(a2, a3)); \
    a0 -= mm_; a1 -= mm_; a2 -= mm_; a3 -= mm_; \
} while (0)

#define BSTEP(E) do { \
    float f0_ = (E).x + b0, f1_ = (E).y + b1, f2_ = (E).z + b2, f3_ = (E).w + b3; \
    float n0_ = l2se3(A.A00 + f0_, A.A01 + f1_, A.A02 + f2_); \
    float n1_ = l2se3(A.A11 + f1_, A.A12 + f2_, A.A13 + f3_); \
    float n2_ = l2se2(A.A22 + f2_, A.A23 + f3_); \
    float n3_ = f3_; \
    float bm_ = fmaxf(fmaxf(n0_, n1_), fmaxf(n2_, n3_)); \
    b0 = n0_ - bm_; b1 = n1_ - bm_; b2 = n2_ - bm_; b3 = n3_ - bm_; \
} while (0)

// gamma -> vals[Q*5 .. Q*5+4]  (uses b0..b3 from enclosing scope)
#define GEMIT(AV, Q) do { \
    float g0_ = (AV).x + b0, g1_ = (AV).y + b1, g2_ = (AV).z + b2, g3_ = (AV).w + b3; \
    float gm_ = fmaxf(fmaxf(g0_, g1_), fmaxf(g2_, g3_)); \
    float q0_ = ex2(g0_ - gm_), q1_ = ex2(g1_ - gm_); \
    float q2_ = ex2(g2_ - gm_), q3_ = ex2(g3_ - gm_); \
    float inv_ = 1.f / (q0_ + q1_ + q2_ + q3_); \
    q0_ *= inv_; q1_ *= inv_; q2_ *= inv_; q3_ *= inv_; \
    vals[(Q)*5 + 0] = fmaf(q0_, wv[0][0], fmaf(q1_, wv[1][0], fmaf(q2_, wv[2][0], q3_ * wv[3][0]))); \
    vals[(Q)*5 + 1] = fmaf(q0_, wv[0][1], fmaf(q1_, wv[1][1], fmaf(q2_, wv[2][1], q3_ * wv[3][1]))); \
    vals[(Q)*5 + 2] = fmaf(q0_, wv[0][2], fmaf(q1_, wv[1][2], fmaf(q2_, wv[2][2], q3_ * wv[3][2]))); \
    vals[(Q)*5 + 3] = fmaf(q0_, wv[0][3], fmaf(q1_, wv[1][3], fmaf(q2_, wv[2][3], q3_ * wv[3][3]))); \
    vals[(Q)*5 + 4] = fmaf(q0_, wv[0][4], fmaf(q1_, wv[1][4], fmaf(q2_, wv[2][4], q3_ * wv[3][4]))); \
} while (0)

// ---------------- pass 1: chunk operators, fwd (z=0) and bwd (z=1) ----------------
__global__ __launch_bounds__(64) void p1_kernel(const float* __restrict__ le,
                                                const float* __restrict__ trans,
                                                float* __restrict__ Mb2,
                                                float* __restrict__ Nb2) {
    int bb = blockIdx.x * 64 + threadIdx.x;
    int c = blockIdx.y;
    bool bz = blockIdx.z != 0;
    TransA A = make_transA(trans);
    const float4* lep = reinterpret_cast<const float4*>(le) + bb;
    int t0 = c * L_CHUNK;
    int base = t0 + (bz ? 1 : 0);

    float4 lb[L_CHUNK];
    #pragma unroll
    for (int k = 0; k < L_CHUNK; ++k) {
        int t = base + k; if (t > TDIM - 1) t = TDIM - 1;
        lb[k] = lep[(size_t)t * BDIM];
    }

    UT M;
    if (!bz) {
        float4 e0 = lb[0];
        if (c == 0) {
            M.m00 = e0.x; M.m11 = e0.y; M.m22 = e0.z; M.m33 = e0.w;
            M.m01 = NEGF; M.m02 = NEGF; M.m03 = NEGF; M.m12 = NEGF; M.m13 = NEGF; M.m23 = NEGF;
        } else {
            M.m00 = A.A00 + e0.x; M.m01 = A.A01 + e0.y; M.m02 = A.A02 + e0.z; M.m03 = NEGF;
            M.m11 = A.A11 + e0.y; M.m12 = A.A12 + e0.z; M.m13 = A.A13 + e0.w;
            M.m22 = A.A22 + e0.z; M.m23 = A.A23 + e0.w; M.m33 = e0.w;
        }
        #pragma unroll
        for (int k = 1; k < L_CHUNK; ++k) fstep(M, A, lb[k]);
        float4* o = reinterpret_cast<float4*>(Mb2) + (size_t)c * 4 * BDIM + bb;
        o[0 * BDIM] = make_float4(M.m00, NEGF,  NEGF,  NEGF );
        o[1 * BDIM] = make_float4(M.m11, M.m01, NEGF,  NEGF );
        o[2 * BDIM] = make_float4(M.m22, NEGF,  M.m02, M.m12);
        o[3 * BDIM] = make_float4(M.m33, M.m23, M.m13, M.m03);
    } else {
        M.m00 = 0.f; M.m11 = 0.f; M.m22 = 0.f; M.m33 = 0.f;
        M.m01 = NEGF; M.m02 = NEGF; M.m03 = NEGF; M.m12 = NEGF; M.m13 = NEGF; M.m23 = NEGF;
        int jmax = (c == C_CHUNK - 1) ? (TDIM - 1) : (t0 + L_CHUNK);
        #pragma unroll
        for (int k = 0; k < L_CHUNK; ++k) {
            if (t0 + 1 + k <= jmax) fstep(M, A, lb[k]);
        }
        float4* o = reinterpret_cast<float4*>(Nb2) + (size_t)c * 4 * BDIM + bb;
        o[0 * BDIM] = make_float4(M.m00, M.m01, M.m02, M.m03);
        o[1 * BDIM] = make_float4(M.m11, NEGF,  M.m13, M.m12);
        o[2 * BDIM] = make_float4(M.m22, M.m23, NEGF,  NEGF );
        o[3 * BDIM] = make_float4(M.m33, NEGF,  NEGF,  NEGF );
    }
}

// ---------------- fused lane-parallel scans ----------------
__global__ __launch_bounds__(64) void scan_kernel(const float* __restrict__ Mb2,
                                                  const float* __restrict__ Nb2,
                                                  const float* __restrict__ initl,
                                                  float* __restrict__ vin,
                                                  float* __restrict__ wbuf) {
    int tid = threadIdx.x;
    int lane = tid & 7;
    int j = lane & 3;
    bool bwd = (lane & 4) != 0;
    int b = blockIdx.x * 8 + (tid >> 3);

    float v;
    if (!bwd) {
        float i0 = initl[0], i1 = initl[1], i2 = initl[2], i3 = initl[3];
        float m = fmaxf(fmaxf(i0, i1), fmaxf(i2, i3));
        float lz = m + __logf(__expf(i0 - m) + __expf(i1 - m) + __expf(i2 - m) + __expf(i3 - m));
        float ij = (j == 0) ? i0 : (j == 1) ? i1 : (j == 2) ? i2 : i3;
        v = (ij - lz) * LOG2E;
    } else {
        v = 0.f;
    }

    const float4* mp = reinterpret_cast<const float4*>(bwd ? Nb2 : Mb2);
    float* op = bwd ? wbuf : vin;

    int c0 = bwd ? (C_CHUNK - 1) : 0;
    int c1 = bwd ? (C_CHUNK - 2) : 1;
    float4 m0 = mp[(size_t)(c0 * 4 + j) * BDIM + b];
    float4 m1 = mp[(size_t)(c1 * 4 + j) * BDIM + b];

    for (int s = 0; s < C_CHUNK; ++s) {
        int c = bwd ? (C_CHUNK - 1 - s) : s;
        float4 mc = m0;
        m0 = m1;
        int s2 = s + 2; if (s2 > C_CHUNK - 1) s2 = C_CHUNK - 1;
        int c2 = bwd ? (C_CHUNK - 1 - s2) : s2;
        m1 = mp[(size_t)(c2 * 4 + j) * BDIM + b];

        op[(size_t)(c * 4 + j) * BDIM + b] = v;   // boundary BEFORE applying op

        float v1 = __shfl_xor(v, 1, 64);
        float v2 = __shfl_xor(v, 2, 64);
        float v3 = __shfl_xor(v1, 2, 64);
        float n = l2se4(v + mc.x, v1 + mc.y, v2 + mc.z, v3 + mc.w);
        float q = fmaxf(n, __shfl_xor(n, 1, 64));
        q = fmaxf(q, __shfl_xor(q, 2, 64));
        v = n - q;
    }
}

// ---------------- pass 2: paired fwd/bwd waves, emit fused ----------------
// Block = 128 threads: wave0 = forward replay, wave1 = backward replay.
// Each wave serial depth ~32 steps + 16 emits (vs 64+32 single-wave).
__global__ __launch_bounds__(128) void p2_kernel(const float* __restrict__ le,
                                                 const float* __restrict__ vin,
                                                 const float* __restrict__ wbuf,
                                                 const float* __restrict__ trans,
                                                 const float* __restrict__ w,
                                                 float* __restrict__ out) {
    __shared__ float4 sh_a[16][64];   // alpha[t0+0 .. t0+15]
    __shared__ float4 sh_b[16][64];   // beta [t0+16 .. t0+31]
    int tid = threadIdx.x;
    int lane = tid & 63;
    int bb = blockIdx.x * 64 + lane;
    int c = blockIdx.y;
    TransA A = make_transA(trans);

    float wv[SDIM][5];
    #pragma unroll
    for (int s = 0; s < SDIM; ++s)
        #pragma unroll
        for (int o = 0; o < 5; ++o) wv[s][o] = w[s * 5 + o];

    const float4* lep = reinterpret_cast<const float4*>(le) + bb;
    int t0 = c * L_CHUNK;
    float* op = out + (size_t)bb * TDIM * 5;
    float vals[20];

    if (tid < 64) {
        // -------- forward wave --------
        float4 lb[L_CHUNK];
        #pragma unroll
        for (int k = 0; k < L_CHUNK; ++k) lb[k] = lep[(size_t)(t0 + k) * BDIM];

        float a0 = vin[((size_t)c * 4 + 0) * BDIM + bb];
        float a1 = vin[((size_t)c * 4 + 1) * BDIM + bb];
        float a2 = vin[((size_t)c * 4 + 2) * BDIM + bb];
        float a3 = vin[((size_t)c * 4 + 3) * BDIM + bb];

        if (c == 0) {
            a0 += lb[0].x; a1 += lb[0].y; a2 += lb[0].z; a3 += lb[0].w;
            float mm = fmaxf(fmaxf(a0, a1), fmaxf(a2, a3));
            a0 -= mm; a1 -= mm; a2 -= mm; a3 -= mm;
        } else {
            ASTEP(lb[0]);
        }
        sh_a[0][lane] = make_float4(a0, a1, a2, a3);
        #pragma unroll
        for (int k = 1; k < 16; ++k) {
            ASTEP(lb[k]);
            sh_a[k][lane] = make_float4(a0, a1, a2, a3);
        }
        __syncthreads();
        float b0, b1, b2, b3;
        #pragma unroll
        for (int g = 4; g < 8; ++g) {
            #pragma unroll
            for (int q = 0; q < 4; ++q) {
                int k = g * 4 + q;
                ASTEP(lb[k]);
                float4 bv = sh_b[k - 16][lane];
                b0 = bv.x; b1 = bv.y; b2 = bv.z; b3 = bv.w;
                float4 av = make_float4(a0, a1, a2, a3);
                GEMIT(av, q);
            }
            float4* vo = reinterpret_cast<float4*>(op + (size_t)(t0 + g * 4) * 5);
            vo[0] = make_float4(vals[0],  vals[1],  vals[2],  vals[3]);
            vo[1] = make_float4(vals[4],  vals[5],  vals[6],  vals[7]);
            vo[2] = make_float4(vals[8],  vals[9],  vals[10], vals[11]);
            vo[3] = make_float4(vals[12], vals[13], vals[14], vals[15]);
            vo[4] = make_float4(vals[16], vals[17], vals[18], vals[19]);
        }
    } else {
        // -------- backward wave --------
        float4 eb[L_CHUNK];   // eb[k] = le[t0+1+k] = e_{t+1} for t = t0+k
        #pragma unroll
        for (int k = 0; k < L_CHUNK; ++k) {
            int t = t0 + 1 + k; if (t > TDIM - 1) t = TDIM - 1;
            eb[k] = lep[(size_t)t * BDIM];
        }

        float b0 = wbuf[((size_t)c * 4 + 0) * BDIM + bb];
        float b1 = wbuf[((size_t)c * 4 + 1) * BDIM + bb];
        float b2 = wbuf[((size_t)c * 4 + 2) * BDIM + bb];
        float b3 = wbuf[((size_t)c * 4 + 3) * BDIM + bb];
        bool lastc = (c == C_CHUNK - 1);

        #pragma unroll
        for (int k = 31; k >= 16; --k) {
            if (!(lastc && k == 31)) BSTEP(eb[k]);   // last chunk: beta[T-1] = wbuf = 0
            sh_b[k - 16][lane] = make_float4(b0, b1, b2, b3);
        }
        __syncthreads();
        #pragma unroll
        for (int g = 3; g >= 0; --g) {
            #pragma unroll
            for (int q = 3; q >= 0; --q) {
                int k = g * 4 + q;
                BSTEP(eb[k]);
                float4 av = sh_a[k][lane];
                GEMIT(av, q);
            }
            float4* vo = reinterpret_cast<float4*>(op + (size_t)(t0 + g * 4) * 5);
            vo[0] = make_float4(vals[0],  vals[1],  vals[2],  vals[3]);
            vo[1] = make_float4(vals[4],  vals[5],  vals[6],  vals[7]);
            vo[2] = make_float4(vals[8],  vals[9],  vals[10], vals[11]);
            vo[3] = make_float4(vals[12], vals[13], vals[14], vals[15]);
            vo[4] = make_float4(vals[16], vals[17], vals[18], vals[19]);
        }
    }
}

extern "C" void kernel_launch(void* const* d_in, const int* in_sizes, int n_in,
                              void* d_out, int out_size, void* d_ws, size_t ws_size,
                              hipStream_t stream) {
    const float* x     = (const float*)d_in[0];
    const float* emit  = (const float*)d_in[1];
    const float* trans = (const float*)d_in[2];
    const float* initl = (const float*)d_in[3];
    const float* w     = (const float*)d_in[4];
    float* out = (float*)d_out;

    const size_t LE_BYTES = (size_t)TDIM * BDIM * SDIM * 4;          // 16 MB
    const size_t OP_BYTES = (size_t)C_CHUNK * 4 * BDIM * 4 * 4;      // 2 MB
    const size_t VB_BYTES = (size_t)C_CHUNK * 4 * BDIM * 4;          // 512 KB

    char* p = (char*)d_ws;
    float* le   = (float*)p;                 p += LE_BYTES;
    float* Mb2  = (float*)p;                 p += OP_BYTES;
    float* Nb2  = (float*)p;                 p += OP_BYTES;
    float* vin  = (float*)p;                 p += VB_BYTES;
    float* wbuf = (float*)p;

    hipLaunchKernelGGL(le_kernel, dim3(BDIM * TDIM / 256), dim3(256), 0, stream, x, emit, le);
    hipLaunchKernelGGL(p1_kernel, dim3(BDIM / 64, C_CHUNK, 2), dim3(64), 0, stream, le, trans, Mb2, Nb2);
    hipLaunchKernelGGL(scan_kernel, dim3(BDIM * 8 / 64), dim3(64), 0, stream, Mb2, Nb2, initl, vin, wbuf);
    hipLaunchKernelGGL(p2_kernel, dim3(BDIM / 64, C_CHUNK), dim3(128), 0, stream, le, vin, wbuf, trans, w, out);
}